// Round 4
// baseline (903.267 us; speedup 1.0000x reference)
//
#include <hip/hip_runtime.h>
#include <stdint.h>

#define DIM 3072
#define HEADS 24
#define HD 128
#define RANKN 64
#define CONDN 1024
#define BLK 2048
#define SEQN 3072
#define NIPN 64

typedef __attribute__((ext_vector_type(8))) short s8v;
typedef __attribute__((ext_vector_type(4))) float fx4;

static __device__ __forceinline__ unsigned short f2bf(float f){
  union{float f; unsigned u;} v; v.f=f;
  unsigned r = v.u + 0x7FFFu + ((v.u>>16)&1u);
  return (unsigned short)(r>>16);
}

#define GL16(g,l) __builtin_amdgcn_global_load_lds((const __attribute__((address_space(1))) void*)(g), (__attribute__((address_space(3))) void*)(l), 16, 0, 0)
#define MFMA(a,b,c) __builtin_amdgcn_mfma_f32_16x16x32_bf16((a),(b),(c),0,0,0)

// ---------------- fp32 -> bf16 convert (4 elems/thread) ----------------
__global__ __launch_bounds__(256) void cvt_f32_bf16(const float* __restrict__ src,
                                                    unsigned short* __restrict__ dst, int n4){
  int i = blockIdx.x*256 + threadIdx.x;
  if (i < n4){
    float4 v = ((const float4*)src)[i];
    ushort4 o;
    o.x = f2bf(v.x); o.y = f2bf(v.y); o.z = f2bf(v.z); o.w = f2bf(v.w);
    ((ushort4*)dst)[i] = o;
  }
}

// ---------------- bf16 GEMM: C[M][N] = A[M][K] * B[N][K]^T (+bias) ----------------
#define BM 128
#define BN 128
#define BK 64
__global__ __launch_bounds__(256) void gemm_bf16(const unsigned short* __restrict__ A,
                                                 const unsigned short* __restrict__ B,
                                                 float* __restrict__ C,
                                                 const float* __restrict__ bias,
                                                 int M){
  const int K = DIM, N = DIM;
  __shared__ unsigned short As[BM*BK];
  __shared__ unsigned short Bs[BN*BK];
  int tid = threadIdx.x;
  int lane = tid & 63, w = tid >> 6;
  int l15 = lane & 15, l16 = lane >> 4;
  int m0 = blockIdx.y * BM, n0 = blockIdx.x * BN;
  int wr = (w >> 1) * 64, wc = (w & 1) * 64;

  fx4 acc[4][4] = {};

  for (int kt = 0; kt < K; kt += BK){
    #pragma unroll
    for (int i = 0; i < 4; i++){
      int p = i*256 + tid;
      int row = p >> 3, cc = p & 7;
      int gc = cc ^ (row & 7);
      int arow = m0 + row; if (arow > M-1) arow = M-1;
      GL16(A + (size_t)arow*K + kt + gc*8, As + p*8);
      GL16(B + (size_t)(n0+row)*K + kt + gc*8, Bs + p*8);
    }
    __syncthreads();
    #pragma unroll
    for (int kk = 0; kk < 2; kk++){
      s8v af[4], bfr[4];
      #pragma unroll
      for (int t = 0; t < 4; t++){
        int rowa = wr + t*16 + l15;
        int ca = (kk*4 + l16) ^ (rowa & 7);
        af[t] = *(const s8v*)(As + rowa*BK + ca*8);
        int rowb = wc + t*16 + l15;
        int cb = (kk*4 + l16) ^ (rowb & 7);
        bfr[t] = *(const s8v*)(Bs + rowb*BK + cb*8);
      }
      #pragma unroll
      for (int mt = 0; mt < 4; mt++)
        #pragma unroll
        for (int nt = 0; nt < 4; nt++)
          acc[mt][nt] = MFMA(af[mt], bfr[nt], acc[mt][nt]);
    }
    __syncthreads();
  }
  #pragma unroll
  for (int mt = 0; mt < 4; mt++){
    #pragma unroll
    for (int j = 0; j < 4; j++){
      int row = m0 + wr + mt*16 + l16*4 + j;
      if (row < M){
        #pragma unroll
        for (int nt = 0; nt < 4; nt++){
          int col = n0 + wc + nt*16 + l15;
          float v = acc[mt][nt][j];
          if (bias) v += bias[col];
          C[(size_t)row*N + col] = v;
        }
      }
    }
  }
}

// ---------------- LoRA down (MFMA): downb[z][1024][64] = hs_bf[2048:] @ downW^T ----------------
__global__ __launch_bounds__(256) void lora_down_g(const unsigned short* __restrict__ A,
                                                   const unsigned short* __restrict__ D0,
                                                   const unsigned short* __restrict__ D1,
                                                   const unsigned short* __restrict__ D2,
                                                   unsigned short* __restrict__ outb){
  __shared__ unsigned short As[128*64];
  __shared__ unsigned short Bs[64*64];
  int tid = threadIdx.x, lane = tid & 63, w = tid >> 6;
  int l15 = lane & 15, l16 = lane >> 4;
  int z = blockIdx.z;
  int m0 = blockIdx.y * 128;
  const unsigned short* Dw = (z==0)?D0:((z==1)?D1:D2);
  int wr = w * 32;
  fx4 acc[2][4] = {};
  for (int kt = 0; kt < DIM; kt += 64){
    #pragma unroll
    for (int i = 0; i < 4; i++){
      int p = i*256 + tid;
      int row = p >> 3, cc = p & 7;
      int gc = cc ^ (row & 7);
      GL16(A + (size_t)(m0+row)*DIM + kt + gc*8, As + p*8);
    }
    #pragma unroll
    for (int i = 0; i < 2; i++){
      int p = i*256 + tid;
      int row = p >> 3, cc = p & 7;
      int gc = cc ^ (row & 7);
      GL16(Dw + (size_t)row*DIM + kt + gc*8, Bs + p*8);
    }
    __syncthreads();
    #pragma unroll
    for (int kk = 0; kk < 2; kk++){
      s8v af[2], bfr[4];
      #pragma unroll
      for (int t = 0; t < 2; t++){
        int rowa = wr + t*16 + l15;
        int ca = (kk*4 + l16) ^ (rowa & 7);
        af[t] = *(const s8v*)(As + rowa*64 + ca*8);
      }
      #pragma unroll
      for (int t = 0; t < 4; t++){
        int rowb = t*16 + l15;
        int cb = (kk*4 + l16) ^ (rowb & 7);
        bfr[t] = *(const s8v*)(Bs + rowb*64 + cb*8);
      }
      #pragma unroll
      for (int mt = 0; mt < 2; mt++)
        #pragma unroll
        for (int nt = 0; nt < 4; nt++)
          acc[mt][nt] = MFMA(af[mt], bfr[nt], acc[mt][nt]);
    }
    __syncthreads();
  }
  #pragma unroll
  for (int mt = 0; mt < 2; mt++)
    #pragma unroll
    for (int j = 0; j < 4; j++){
      int row = m0 + wr + mt*16 + l16*4 + j;
      #pragma unroll
      for (int nt = 0; nt < 4; nt++){
        int col = nt*16 + l15;
        outb[((size_t)z*CONDN + row)*64 + col] = f2bf(acc[mt][nt][j]);
      }
    }
}

// ---------------- LoRA up (MFMA): q/k/v rows [2048:3072) += downb @ upW^T ----------------
__global__ __launch_bounds__(256) void lora_up_g(const unsigned short* __restrict__ downb,
                                                 const unsigned short* __restrict__ U0,
                                                 const unsigned short* __restrict__ U1,
                                                 const unsigned short* __restrict__ U2,
                                                 float* __restrict__ q,
                                                 float* __restrict__ k,
                                                 float* __restrict__ v){
  __shared__ unsigned short As[128*64];
  __shared__ unsigned short Bs[128*64];
  int tid = threadIdx.x, lane = tid & 63, w = tid >> 6;
  int l15 = lane & 15, l16 = lane >> 4;
  int z = blockIdx.z;
  int m0 = blockIdx.y * 128, n0 = blockIdx.x * 128;
  const unsigned short* A = downb + (size_t)z*CONDN*64;
  const unsigned short* B = (z==0)?U0:((z==1)?U1:U2);
  float* dst = ((z==0)?q:((z==1)?k:v)) + (size_t)BLK*DIM;
  int wr = (w >> 1) * 64, wc = (w & 1) * 64;
  fx4 acc[4][4] = {};
  #pragma unroll
  for (int i = 0; i < 4; i++){
    int p = i*256 + tid;
    int row = p >> 3, cc = p & 7;
    int gc = cc ^ (row & 7);
    GL16(A + (size_t)(m0+row)*64 + gc*8, As + p*8);
    GL16(B + (size_t)(n0+row)*64 + gc*8, Bs + p*8);
  }
  __syncthreads();
  #pragma unroll
  for (int kk = 0; kk < 2; kk++){
    s8v af[4], bfr[4];
    #pragma unroll
    for (int t = 0; t < 4; t++){
      int rowa = wr + t*16 + l15;
      int ca = (kk*4 + l16) ^ (rowa & 7);
      af[t] = *(const s8v*)(As + rowa*64 + ca*8);
      int rowb = wc + t*16 + l15;
      int cb = (kk*4 + l16) ^ (rowb & 7);
      bfr[t] = *(const s8v*)(Bs + rowb*64 + cb*8);
    }
    #pragma unroll
    for (int mt = 0; mt < 4; mt++)
      #pragma unroll
      for (int nt = 0; nt < 4; nt++)
        acc[mt][nt] = MFMA(af[mt], bfr[nt], acc[mt][nt]);
  }
  #pragma unroll
  for (int mt = 0; mt < 4; mt++)
    #pragma unroll
    for (int j = 0; j < 4; j++){
      int row = m0 + wr + mt*16 + l16*4 + j;
      float* drow = dst + (size_t)row*DIM;
      #pragma unroll
      for (int nt = 0; nt < 4; nt++){
        int col = n0 + wc + nt*16 + l15;
        drow[col] += acc[mt][nt][j];
      }
    }
}

// ---------------- rmsnorm + rope -> bf16 head-major [H][S][HD], output scaled by qscale ----------------
__global__ __launch_bounds__(256) void norm_rope(const float* __restrict__ src,
                                                 unsigned short* __restrict__ dst,
                                                 const float* __restrict__ wt,
                                                 const float* __restrict__ rc,
                                                 const float* __restrict__ rs,
                                                 int S, float qscale){
  int tid = threadIdx.x, lane = tid & 63, w = tid >> 6;
  int r = blockIdx.x*4 + w;
  int pos = r % S, h = r / S;
  const float* x = src + (size_t)pos*DIM + h*HD;
  float2 xv = *(const float2*)(x + 2*lane);
  float ss = xv.x*xv.x + xv.y*xv.y;
  #pragma unroll
  for (int o = 1; o < 64; o <<= 1) ss += __shfl_xor(ss, o);
  float rr = rsqrtf(ss*(1.f/128.f) + 1e-6f);
  float y0 = xv.x*rr*wt[2*lane], y1 = xv.y*rr*wt[2*lane+1];
  float2 cv = *(const float2*)(rc + (size_t)pos*HD + 2*lane);
  float2 sv = *(const float2*)(rs + (size_t)pos*HD + 2*lane);
  float o0 = (y0*cv.x - y1*sv.x)*qscale;
  float o1 = (y1*cv.y + y0*sv.y)*qscale;
  ushort2 ov; ov.x = f2bf(o0); ov.y = f2bf(o1);
  *(ushort2*)(dst + ((size_t)h*S + pos)*HD + 2*lane) = ov;
}

// ---------------- ip_k rmsnorm (eps 1e-5, no weight) -> bf16 [H][64][HD] ----------------
__global__ __launch_bounds__(256) void ipk_norm_bf(const float* __restrict__ src,
                                                   unsigned short* __restrict__ dst){
  int tid = threadIdx.x, lane = tid & 63, w = tid >> 6;
  int r = blockIdx.x*4 + w;         // r < 64*24
  int pos = r / HEADS, h = r % HEADS;
  const float* x = src + (size_t)pos*DIM + h*HD;
  float2 xv = *(const float2*)(x + 2*lane);
  float ss = xv.x*xv.x + xv.y*xv.y;
  #pragma unroll
  for (int o = 1; o < 64; o <<= 1) ss += __shfl_xor(ss, o);
  float rr = rsqrtf(ss*(1.f/128.f) + 1e-5f);
  ushort2 ov; ov.x = f2bf(xv.x*rr); ov.y = f2bf(xv.y*rr);
  *(ushort2*)(dst + ((size_t)h*NIPN + pos)*HD + 2*lane) = ov;
}

// ---------------- ipv -> bf16 [H][HD][64] transpose ----------------
__global__ __launch_bounds__(256) void ipv_transpose(const float* __restrict__ ipv,
                                                     unsigned short* __restrict__ vt){
  int h = blockIdx.x, tid = threadIdx.x;
  #pragma unroll
  for (int i = 0; i < 32; i++){
    int idx = i*256 + tid;       // idx = d*64 + key
    int d = idx >> 6, key = idx & 63;
    vt[((size_t)h*HD + d)*64 + key] = f2bf(ipv[(size_t)key*DIM + h*HD + d]);
  }
}

// ---------------- v -> Vt bf16 [H][HD][SEQ] transpose ----------------
__global__ __launch_bounds__(256) void v_transpose(const float* __restrict__ v,
                                                   unsigned short* __restrict__ Vt){
  __shared__ float t[64][129];
  int h = blockIdx.y, p0 = blockIdx.x*64, tid = threadIdx.x;
  int dcol = tid & 127, prow2 = tid >> 7;
  #pragma unroll
  for (int i = 0; i < 32; i++){
    int pos = i*2 + prow2;
    t[pos][dcol] = v[(size_t)(p0+pos)*DIM + h*HD + dcol];
  }
  __syncthreads();
  int pos = tid & 63, dbase = tid >> 6;
  #pragma unroll
  for (int i = 0; i < 32; i++){
    int d = i*4 + dbase;
    Vt[((size_t)h*HD + d)*SEQN + p0 + pos] = f2bf(t[pos][d]);
  }
}

// ---------------- IP attention (MFMA): 2048 q x 64 keys per head, exact softmax ----------------
__global__ __launch_bounds__(256) void ip_attn_m(const float* __restrict__ qb,
                                                 const unsigned short* __restrict__ ipk_bf,
                                                 const unsigned short* __restrict__ ipv_t,
                                                 float* __restrict__ out){
  __shared__ unsigned short Ks[64*HD];
  __shared__ unsigned short Vs[HD*64];
  __shared__ unsigned short Ps[4][16*64];
  int tid = threadIdx.x, lane = tid & 63, w = tid >> 6;
  int l15 = lane & 15, l16 = lane >> 4;
  int h = blockIdx.y;
  int q0 = blockIdx.x*64 + w*16;
  const unsigned short* Kh = ipk_bf + (size_t)h*NIPN*HD;
  const unsigned short* Vh = ipv_t + (size_t)h*HD*NIPN;

  #pragma unroll
  for (int i = 0; i < 4; i++){
    int p = i*256 + tid;
    int row = p >> 4, cc = p & 15;
    int gc = cc ^ (row & 7);
    GL16(Kh + (size_t)row*HD + gc*8, Ks + p*8);
  }
  #pragma unroll
  for (int i = 0; i < 4; i++){
    int p = i*256 + tid;
    int row = p >> 3, cc = p & 7;
    int gc = cc ^ (row & 7);
    GL16(Vh + (size_t)row*64 + gc*8, Vs + p*8);
  }

  // q fragments from fp32 qb (original_query = pre-norm q, rows < 2048)
  s8v qf[4];
  #pragma unroll
  for (int kf = 0; kf < 4; kf++){
    const float* qp = qb + (size_t)(q0 + l15)*DIM + h*HD + kf*32 + l16*8;
    float4 a = *(const float4*)qp;
    float4 b = *(const float4*)(qp + 4);
    s8v f;
    f[0]=(short)f2bf(a.x); f[1]=(short)f2bf(a.y); f[2]=(short)f2bf(a.z); f[3]=(short)f2bf(a.w);
    f[4]=(short)f2bf(b.x); f[5]=(short)f2bf(b.y); f[6]=(short)f2bf(b.z); f[7]=(short)f2bf(b.w);
    qf[kf] = f;
  }
  __syncthreads();

  fx4 s[4] = {};
  #pragma unroll
  for (int ct = 0; ct < 4; ct++){
    #pragma unroll
    for (int kk = 0; kk < 4; kk++){
      int row = ct*16 + l15;
      int c = (kk*4 + l16) ^ (row & 7);
      s8v b = *(const s8v*)(Ks + row*HD + c*8);
      s[ct] = MFMA(qf[kk], b, s[ct]);
    }
  }
  const float SC = 0.08838834764831845f;
  float lrow[4];
  #pragma unroll
  for (int j = 0; j < 4; j++){
    #pragma unroll
    for (int ct = 0; ct < 4; ct++) s[ct][j] *= SC;
    float v = fmaxf(fmaxf(s[0][j], s[1][j]), fmaxf(s[2][j], s[3][j]));
    #pragma unroll
    for (int o2 = 1; o2 < 16; o2 <<= 1) v = fmaxf(v, __shfl_xor(v, o2));
    float sum = 0.f;
    #pragma unroll
    for (int ct = 0; ct < 4; ct++){
      float p = __expf(s[ct][j] - v);
      s[ct][j] = p;
      sum += p;
    }
    #pragma unroll
    for (int o2 = 1; o2 < 16; o2 <<= 1) sum += __shfl_xor(sum, o2);
    lrow[j] = sum;
  }

  // P -> bf16 via swizzled per-wave LDS
  #pragma unroll
  for (int ct = 0; ct < 4; ct++)
    #pragma unroll
    for (int j = 0; j < 4; j++){
      int row = l16*4 + j;
      int cidx = ct*16 + l15;
      Ps[w][row*64 + (((cidx>>3) ^ (row&7))<<3) + (cidx&7)] = f2bf(s[ct][j]);
    }
  asm volatile("s_waitcnt lgkmcnt(0)" ::: "memory");
  s8v pa[2];
  #pragma unroll
  for (int kk = 0; kk < 2; kk++){
    int c = (kk*4 + l16) ^ (l15 & 7);
    pa[kk] = *(const s8v*)(&Ps[w][l15*64 + c*8]);
  }
  fx4 o[8] = {};
  #pragma unroll
  for (int nt = 0; nt < 8; nt++){
    #pragma unroll
    for (int kk = 0; kk < 2; kk++){
      int row = nt*16 + l15;
      int c = (kk*4 + l16) ^ (row & 7);
      s8v bv = *(const s8v*)(Vs + row*64 + c*8);
      o[nt] = MFMA(pa[kk], bv, o[nt]);
    }
  }
  #pragma unroll
  for (int nt = 0; nt < 8; nt++)
    #pragma unroll
    for (int j = 0; j < 4; j++){
      int row = q0 + l16*4 + j;
      int d = nt*16 + l15;
      out[(size_t)row*DIM + h*HD + d] = o[nt][j] / lrow[j];
    }
}

// ---------------- main flash attention, split-K x2, double-buffered KV ----------------
#define QB 64
#define KVB 64
#define PSTR 72
__global__ __launch_bounds__(256) void flash_attn_split(const unsigned short* __restrict__ Qn,
                                                        const unsigned short* __restrict__ Kn,
                                                        const unsigned short* __restrict__ Vt,
                                                        float* __restrict__ po0,
                                                        float* __restrict__ po1,
                                                        float* __restrict__ pm,
                                                        float* __restrict__ pl){
  __shared__ unsigned short Ks[2][KVB*HD];
  __shared__ unsigned short Vs[2][HD*KVB];
  __shared__ unsigned short Ps[4][16*PSTR];
  int tid = threadIdx.x, lane = tid & 63, w = tid >> 6;
  int l15 = lane & 15, l16 = lane >> 4;
  int h = blockIdx.y, sp = blockIdx.z;
  int q0 = blockIdx.x*QB + w*16;
  const unsigned short* Qh = Qn + (size_t)h*BLK*HD;
  const unsigned short* Kh = Kn + (size_t)h*SEQN*HD;
  const unsigned short* Vh = Vt + (size_t)h*HD*SEQN;
  const int kvbase = sp * (SEQN/2);
  const int NT = (SEQN/2) / KVB;   // 24 tiles

  auto STAGE = [&](int b, int kv0){
    #pragma unroll
    for (int i = 0; i < 4; i++){
      int p = i*256 + tid;
      int row = p >> 4, cc = p & 15;
      int gc = cc ^ (row & 7);
      GL16(Kh + (size_t)(kv0+row)*HD + gc*8, &Ks[b][p*8]);
    }
    #pragma unroll
    for (int i = 0; i < 4; i++){
      int p = i*256 + tid;
      int row = p >> 3, cc = p & 7;
      int gc = cc ^ (row & 7);
      GL16(Vh + (size_t)row*SEQN + kv0 + gc*8, &Vs[b][p*8]);
    }
  };

  s8v qf[4];
  #pragma unroll
  for (int kf = 0; kf < 4; kf++)
    qf[kf] = *(const s8v*)(Qh + (size_t)(q0 + l15)*HD + kf*32 + l16*8);

  fx4 o[8] = {};
  float mrow[4], lrow[4];
  #pragma unroll
  for (int j = 0; j < 4; j++){ mrow[j] = -1e30f; lrow[j] = 0.f; }

  STAGE(0, kvbase);
  __syncthreads();               // compiler drains vmcnt before barrier
  int cur = 0;

  for (int t = 0; t < NT; t++){
    if (t+1 < NT) STAGE(cur^1, kvbase + (t+1)*KVB);

    fx4 s[4] = {};
    #pragma unroll
    for (int ct = 0; ct < 4; ct++){
      #pragma unroll
      for (int kk = 0; kk < 4; kk++){
        int row = ct*16 + l15;
        int c = (kk*4 + l16) ^ (row & 7);
        s8v b = *(const s8v*)(&Ks[cur][row*HD + c*8]);
        s[ct] = MFMA(qf[kk], b, s[ct]);
      }
    }
    // (scale already folded into Qn)
    float pmax[4], rssum[4];
    #pragma unroll
    for (int j = 0; j < 4; j++){
      float v = fmaxf(fmaxf(s[0][j], s[1][j]), fmaxf(s[2][j], s[3][j]));
      #pragma unroll
      for (int o2 = 1; o2 < 16; o2 <<= 1) v = fmaxf(v, __shfl_xor(v, o2));
      pmax[j] = v;
      rssum[j] = 0.f;
    }
    float need = 0.f;
    #pragma unroll
    for (int j = 0; j < 4; j++) need = fmaxf(need, pmax[j] - mrow[j]);
    if (__any(need > 8.f)){
      float alpha[4];
      #pragma unroll
      for (int j = 0; j < 4; j++){
        float mnew = fmaxf(mrow[j], pmax[j]);
        alpha[j] = __expf(mrow[j] - mnew);
        mrow[j] = mnew;
      }
      #pragma unroll
      for (int nt = 0; nt < 8; nt++)
        #pragma unroll
        for (int j = 0; j < 4; j++) o[nt][j] *= alpha[j];
      #pragma unroll
      for (int j = 0; j < 4; j++) lrow[j] *= alpha[j];
    }
    #pragma unroll
    for (int ct = 0; ct < 4; ct++)
      #pragma unroll
      for (int j = 0; j < 4; j++){
        float p = __expf(s[ct][j] - mrow[j]);
        s[ct][j] = p;
        rssum[j] += p;
      }
    #pragma unroll
    for (int j = 0; j < 4; j++){
      #pragma unroll
      for (int o2 = 1; o2 < 16; o2 <<= 1) rssum[j] += __shfl_xor(rssum[j], o2);
      lrow[j] += rssum[j];
    }

    // P -> bf16 per-wave LDS, stride 72 (bank-spread, no XOR)
    #pragma unroll
    for (int ct = 0; ct < 4; ct++)
      #pragma unroll
      for (int j = 0; j < 4; j++){
        int row = l16*4 + j;
        int cidx = ct*16 + l15;
        Ps[w][row*PSTR + cidx] = f2bf(s[ct][j]);
      }
    asm volatile("s_waitcnt lgkmcnt(0)" ::: "memory");
    s8v pa[2];
    #pragma unroll
    for (int kk = 0; kk < 2; kk++)
      pa[kk] = *(const s8v*)(&Ps[w][l15*PSTR + (kk*4 + l16)*8]);
    #pragma unroll
    for (int nt = 0; nt < 8; nt++){
      #pragma unroll
      for (int kk = 0; kk < 2; kk++){
        int row = nt*16 + l15;
        int c = (kk*4 + l16) ^ (row & 7);
        s8v bv = *(const s8v*)(&Vs[cur][row*KVB + c*8]);
        o[nt] = MFMA(pa[kk], bv, o[nt]);
      }
    }
    __syncthreads();             // drains this iter's STAGE loads + read/write fence
    cur ^= 1;
  }

  float* pop = sp ? po1 : po0;
  #pragma unroll
  for (int nt = 0; nt < 8; nt++)
    #pragma unroll
    for (int j = 0; j < 4; j++){
      int row = q0 + l16*4 + j;
      int d = nt*16 + l15;
      pop[((size_t)h*BLK + row)*HD + d] = o[nt][j];
    }
  if (l15 == 0){
    #pragma unroll
    for (int j = 0; j < 4; j++){
      int row = q0 + l16*4 + j;
      pm[(size_t)sp*HEADS*BLK + h*BLK + row] = mrow[j];
      pl[(size_t)sp*HEADS*BLK + h*BLK + row] = lrow[j];
    }
  }
}

// ---------------- merge the two split-K halves into out (+=) ----------------
__global__ __launch_bounds__(256) void flash_merge(const float* __restrict__ po0,
                                                   const float* __restrict__ po1,
                                                   const float* __restrict__ pm,
                                                   const float* __restrict__ pl,
                                                   float* __restrict__ out){
  int tid = threadIdx.x, lane = tid & 63, w = tid >> 6;
  int r = blockIdx.x*4 + w;        // r < HEADS*BLK
  int h = r >> 11, pos = r & 2047;
  float m0 = pm[r], m1 = pm[HEADS*BLK + r];
  float l0 = pl[r], l1 = pl[HEADS*BLK + r];
  float mx = fmaxf(m0, m1);
  float a0 = __expf(m0 - mx), a1 = __expf(m1 - mx);
  float li = 1.f / (l0*a0 + l1*a1);
  float s0 = a0*li, s1 = a1*li;
  size_t base = ((size_t)h*BLK + pos)*HD + 2*lane;
  float2 x0 = *(const float2*)(po0 + base);
  float2 x1 = *(const float2*)(po1 + base);
  float* op = out + (size_t)pos*DIM + h*HD + 2*lane;
  float2 cv = *(const float2*)op;
  cv.x += x0.x*s0 + x1.x*s1;
  cv.y += x0.y*s0 + x1.y*s1;
  *(float2*)op = cv;
}

extern "C" void kernel_launch(void* const* d_in, const int* in_sizes, int n_in,
                              void* d_out, int out_size, void* d_ws, size_t ws_size,
                              hipStream_t stream){
  (void)in_sizes; (void)n_in; (void)out_size;
  const float* hs       = (const float*)d_in[0];
  const float* image_emb= (const float*)d_in[1];
  const float* rope_cos = (const float*)d_in[2];
  const float* rope_sin = (const float*)d_in[3];
  const float* wq = (const float*)d_in[4];
  const float* bq = (const float*)d_in[5];
  const float* wk = (const float*)d_in[6];
  const float* bk = (const float*)d_in[7];
  const float* wv = (const float*)d_in[8];
  const float* bv = (const float*)d_in[9];
  const float* norm_q_w = (const float*)d_in[10];
  const float* norm_k_w = (const float*)d_in[11];
  const float* q_down = (const float*)d_in[12];
  const float* q_up   = (const float*)d_in[13];
  const float* k_down = (const float*)d_in[14];
  const float* k_up   = (const float*)d_in[15];
  const float* v_down = (const float*)d_in[16];
  const float* v_up   = (const float*)d_in[17];
  const float* wk_ip  = (const float*)d_in[18];
  const float* wv_ip  = (const float*)d_in[19];
  float* out = (float*)d_out;

  char* ws = (char*)d_ws;
  size_t off = 0;
  auto alloc = [&](size_t bytes){ void* p = ws + off; off += (bytes + 255) & ~(size_t)255; return p; };
  unsigned short* hs_bf = (unsigned short*)alloc((size_t)SEQN*DIM*2);
  unsigned short* w_bf  = (unsigned short*)alloc((size_t)DIM*DIM*2);
  unsigned short* ie_bf = (unsigned short*)alloc((size_t)NIPN*DIM*2);
  float* qb = (float*)alloc((size_t)SEQN*DIM*4);
  float* kb = (float*)alloc((size_t)SEQN*DIM*4);
  float* vb = (float*)alloc((size_t)SEQN*DIM*4);
  float* ipk_pre = (float*)alloc((size_t)NIPN*DIM*4);
  float* ipv_pre = (float*)alloc((size_t)NIPN*DIM*4);
  unsigned short* ipk_bf = (unsigned short*)alloc((size_t)HEADS*NIPN*HD*2);
  unsigned short* ipv_t  = (unsigned short*)alloc((size_t)HEADS*HD*NIPN*2);
  unsigned short* dwn_bf[3];
  unsigned short* upw_bf[3];
  for (int i = 0; i < 3; i++) dwn_bf[i] = (unsigned short*)alloc((size_t)RANKN*DIM*2);
  for (int i = 0; i < 3; i++) upw_bf[i] = (unsigned short*)alloc((size_t)DIM*RANKN*2);
  unsigned short* downb_bf = (unsigned short*)alloc((size_t)3*CONDN*RANKN*2);
  unsigned short* Qn = (unsigned short*)alloc((size_t)HEADS*BLK*HD*2);
  unsigned short* Kn = (unsigned short*)alloc((size_t)HEADS*SEQN*HD*2);
  unsigned short* Vt = (unsigned short*)alloc((size_t)HEADS*HD*SEQN*2);
  if (off > ws_size) return;  // workspace too small -> leave output poisoned (visible failure)

  // split-K partials alias dead buffers (qb/kb/vb are fully consumed before flash_attn_split):
  //   po0 needs 24*2048*128*4 = 25.2MB <= qb (37.7MB); po1 <= kb; pm+pl <= vb.
  float* po0 = qb;
  float* po1 = kb;
  float* pm  = vb;
  float* pl  = vb + (size_t)2*HEADS*BLK;

  int n4;
  n4 = SEQN*DIM/4;
  cvt_f32_bf16<<<(n4+255)/256, 256, 0, stream>>>(hs, hs_bf, n4);
  n4 = NIPN*DIM/4;
  cvt_f32_bf16<<<(n4+255)/256, 256, 0, stream>>>(image_emb, ie_bf, n4);

  dim3 gfull(DIM/BN, SEQN/BM);
  dim3 gip(DIM/BN, 1);
  n4 = DIM*DIM/4;
  cvt_f32_bf16<<<(n4+255)/256, 256, 0, stream>>>(wq, w_bf, n4);
  gemm_bf16<<<gfull, 256, 0, stream>>>(hs_bf, w_bf, qb, bq, SEQN);
  cvt_f32_bf16<<<(n4+255)/256, 256, 0, stream>>>(wk, w_bf, n4);
  gemm_bf16<<<gfull, 256, 0, stream>>>(hs_bf, w_bf, kb, bk, SEQN);
  cvt_f32_bf16<<<(n4+255)/256, 256, 0, stream>>>(wv, w_bf, n4);
  gemm_bf16<<<gfull, 256, 0, stream>>>(hs_bf, w_bf, vb, bv, SEQN);
  cvt_f32_bf16<<<(n4+255)/256, 256, 0, stream>>>(wk_ip, w_bf, n4);
  gemm_bf16<<<gip, 256, 0, stream>>>(ie_bf, w_bf, ipk_pre, nullptr, NIPN);
  cvt_f32_bf16<<<(n4+255)/256, 256, 0, stream>>>(wv_ip, w_bf, n4);
  gemm_bf16<<<gip, 256, 0, stream>>>(ie_bf, w_bf, ipv_pre, nullptr, NIPN);

  // LoRA path (MFMA)
  n4 = RANKN*DIM/4;
  cvt_f32_bf16<<<(n4+255)/256, 256, 0, stream>>>(q_down, dwn_bf[0], n4);
  cvt_f32_bf16<<<(n4+255)/256, 256, 0, stream>>>(k_down, dwn_bf[1], n4);
  cvt_f32_bf16<<<(n4+255)/256, 256, 0, stream>>>(v_down, dwn_bf[2], n4);
  cvt_f32_bf16<<<(n4+255)/256, 256, 0, stream>>>(q_up, upw_bf[0], n4);
  cvt_f32_bf16<<<(n4+255)/256, 256, 0, stream>>>(k_up, upw_bf[1], n4);
  cvt_f32_bf16<<<(n4+255)/256, 256, 0, stream>>>(v_up, upw_bf[2], n4);
  lora_down_g<<<dim3(1, CONDN/128, 3), 256, 0, stream>>>(hs_bf + (size_t)BLK*DIM,
      dwn_bf[0], dwn_bf[1], dwn_bf[2], downb_bf);
  lora_up_g<<<dim3(DIM/128, CONDN/128, 3), 256, 0, stream>>>(downb_bf,
      upw_bf[0], upw_bf[1], upw_bf[2], qb, kb, vb);

  ipk_norm_bf<<<(NIPN*HEADS)/4, 256, 0, stream>>>(ipk_pre, ipk_bf);
  ipv_transpose<<<HEADS, 256, 0, stream>>>(ipv_pre, ipv_t);
  const float SC = 0.08838834764831845f;
  norm_rope<<<(BLK*HEADS)/4, 256, 0, stream>>>(qb, Qn, norm_q_w, rope_cos, rope_sin, BLK, SC);
  norm_rope<<<(SEQN*HEADS)/4, 256, 0, stream>>>(kb, Kn, norm_k_w, rope_cos, rope_sin, SEQN, 1.0f);
  v_transpose<<<dim3(SEQN/64, HEADS), 256, 0, stream>>>(vb, Vt);

  ip_attn_m<<<dim3(BLK/64, HEADS), 256, 0, stream>>>(qb, ipk_bf, ipv_t, out);
  // qb/kb/vb are dead from here on: reuse as split-K partial buffers
  flash_attn_split<<<dim3(BLK/QB, HEADS, 2), 256, 0, stream>>>(Qn, Kn, Vt, po0, po1, pm, pl);
  flash_merge<<<(HEADS*BLK)/4, 256, 0, stream>>>(po0, po1, pm, pl, out);
}

// Round 5
// 750.023 us; speedup vs baseline: 1.2043x; 1.2043x over previous
//
#include <hip/hip_runtime.h>
#include <stdint.h>

#define DIM 3072
#define HEADS 24
#define HD 128
#define RANKN 64
#define CONDN 1024
#define BLK 2048
#define SEQN 3072
#define NIPN 64

typedef __attribute__((ext_vector_type(8))) short s8v;
typedef __attribute__((ext_vector_type(4))) float fx4;

static __device__ __forceinline__ unsigned short f2bf(float f){
  union{float f; unsigned u;} v; v.f=f;
  unsigned r = v.u + 0x7FFFu + ((v.u>>16)&1u);
  return (unsigned short)(r>>16);
}

#define GL16(g,l) __builtin_amdgcn_global_load_lds((const __attribute__((address_space(1))) void*)(g), (__attribute__((address_space(3))) void*)(l), 16, 0, 0)
#define MFMA(a,b,c) __builtin_amdgcn_mfma_f32_16x16x32_bf16((a),(b),(c),0,0,0)

// ---------------- fp32 -> bf16 convert (4 elems/thread) ----------------
__global__ __launch_bounds__(256) void cvt_f32_bf16(const float* __restrict__ src,
                                                    unsigned short* __restrict__ dst, int n4){
  int i = blockIdx.x*256 + threadIdx.x;
  if (i < n4){
    float4 v = ((const float4*)src)[i];
    ushort4 o;
    o.x = f2bf(v.x); o.y = f2bf(v.y); o.z = f2bf(v.z); o.w = f2bf(v.w);
    ((ushort4*)dst)[i] = o;
  }
}

// ---------------- bf16 GEMM: C[M][N] = A[M][K] * B[N][K]^T (+bias) ----------------
#define BM 128
#define BN 128
#define BK 64
__global__ __launch_bounds__(256) void gemm_bf16(const unsigned short* __restrict__ A,
                                                 const unsigned short* __restrict__ B,
                                                 float* __restrict__ C,
                                                 const float* __restrict__ bias,
                                                 int M){
  const int K = DIM, N = DIM;
  __shared__ unsigned short As[BM*BK];
  __shared__ unsigned short Bs[BN*BK];
  int tid = threadIdx.x;
  int lane = tid & 63, w = tid >> 6;
  int l15 = lane & 15, l16 = lane >> 4;
  int m0 = blockIdx.y * BM, n0 = blockIdx.x * BN;
  int wr = (w >> 1) * 64, wc = (w & 1) * 64;

  fx4 acc[4][4] = {};

  for (int kt = 0; kt < K; kt += BK){
    #pragma unroll
    for (int i = 0; i < 4; i++){
      int p = i*256 + tid;
      int row = p >> 3, cc = p & 7;
      int gc = cc ^ (row & 7);
      int arow = m0 + row; if (arow > M-1) arow = M-1;
      GL16(A + (size_t)arow*K + kt + gc*8, As + p*8);
      GL16(B + (size_t)(n0+row)*K + kt + gc*8, Bs + p*8);
    }
    __syncthreads();
    #pragma unroll
    for (int kk = 0; kk < 2; kk++){
      s8v af[4], bfr[4];
      #pragma unroll
      for (int t = 0; t < 4; t++){
        int rowa = wr + t*16 + l15;
        int ca = (kk*4 + l16) ^ (rowa & 7);
        af[t] = *(const s8v*)(As + rowa*BK + ca*8);
        int rowb = wc + t*16 + l15;
        int cb = (kk*4 + l16) ^ (rowb & 7);
        bfr[t] = *(const s8v*)(Bs + rowb*BK + cb*8);
      }
      #pragma unroll
      for (int mt = 0; mt < 4; mt++)
        #pragma unroll
        for (int nt = 0; nt < 4; nt++)
          acc[mt][nt] = MFMA(af[mt], bfr[nt], acc[mt][nt]);
    }
    __syncthreads();
  }
  #pragma unroll
  for (int mt = 0; mt < 4; mt++){
    #pragma unroll
    for (int j = 0; j < 4; j++){
      int row = m0 + wr + mt*16 + l16*4 + j;
      if (row < M){
        #pragma unroll
        for (int nt = 0; nt < 4; nt++){
          int col = n0 + wc + nt*16 + l15;
          float v = acc[mt][nt][j];
          if (bias) v += bias[col];
          C[(size_t)row*N + col] = v;
        }
      }
    }
  }
}

// ---------------- fused QKV GEMM: z = blockIdx.x/24 selects W/C/bias ----------------
__global__ __launch_bounds__(256) void gemm_qkv(const unsigned short* __restrict__ A,
                                                const unsigned short* __restrict__ W0,
                                                const unsigned short* __restrict__ W1,
                                                const unsigned short* __restrict__ W2,
                                                float* __restrict__ C0,
                                                float* __restrict__ C1,
                                                float* __restrict__ C2,
                                                const float* __restrict__ b0,
                                                const float* __restrict__ b1,
                                                const float* __restrict__ b2){
  const int K = DIM, N = DIM;
  __shared__ unsigned short As[BM*BK];
  __shared__ unsigned short Bs[BN*BK];
  int tid = threadIdx.x;
  int lane = tid & 63, w = tid >> 6;
  int l15 = lane & 15, l16 = lane >> 4;
  int z = blockIdx.x / 24;
  int m0 = blockIdx.y * BM, n0 = (blockIdx.x % 24) * BN;
  const unsigned short* B = (z==0)?W0:((z==1)?W1:W2);
  float* C = (z==0)?C0:((z==1)?C1:C2);
  const float* bias = (z==0)?b0:((z==1)?b1:b2);
  int wr = (w >> 1) * 64, wc = (w & 1) * 64;

  fx4 acc[4][4] = {};

  for (int kt = 0; kt < K; kt += BK){
    #pragma unroll
    for (int i = 0; i < 4; i++){
      int p = i*256 + tid;
      int row = p >> 3, cc = p & 7;
      int gc = cc ^ (row & 7);
      GL16(A + (size_t)(m0+row)*K + kt + gc*8, As + p*8);
      GL16(B + (size_t)(n0+row)*K + kt + gc*8, Bs + p*8);
    }
    __syncthreads();
    #pragma unroll
    for (int kk = 0; kk < 2; kk++){
      s8v af[4], bfr[4];
      #pragma unroll
      for (int t = 0; t < 4; t++){
        int rowa = wr + t*16 + l15;
        int ca = (kk*4 + l16) ^ (rowa & 7);
        af[t] = *(const s8v*)(As + rowa*BK + ca*8);
        int rowb = wc + t*16 + l15;
        int cb = (kk*4 + l16) ^ (rowb & 7);
        bfr[t] = *(const s8v*)(Bs + rowb*BK + cb*8);
      }
      #pragma unroll
      for (int mt = 0; mt < 4; mt++)
        #pragma unroll
        for (int nt = 0; nt < 4; nt++)
          acc[mt][nt] = MFMA(af[mt], bfr[nt], acc[mt][nt]);
    }
    __syncthreads();
  }
  #pragma unroll
  for (int mt = 0; mt < 4; mt++){
    #pragma unroll
    for (int j = 0; j < 4; j++){
      int row = m0 + wr + mt*16 + l16*4 + j;
      float* crow = C + (size_t)row*N;
      #pragma unroll
      for (int nt = 0; nt < 4; nt++){
        int col = n0 + wc + nt*16 + l15;
        crow[col] = acc[mt][nt][j] + bias[col];
      }
    }
  }
}

// ---------------- LoRA down (MFMA): downb[z][1024][64] = hs_bf[2048:] @ downW^T ----------------
__global__ __launch_bounds__(256) void lora_down_g(const unsigned short* __restrict__ A,
                                                   const unsigned short* __restrict__ D0,
                                                   const unsigned short* __restrict__ D1,
                                                   const unsigned short* __restrict__ D2,
                                                   unsigned short* __restrict__ outb){
  __shared__ unsigned short As[128*64];
  __shared__ unsigned short Bs[64*64];
  int tid = threadIdx.x, lane = tid & 63, w = tid >> 6;
  int l15 = lane & 15, l16 = lane >> 4;
  int z = blockIdx.z;
  int m0 = blockIdx.y * 128;
  const unsigned short* Dw = (z==0)?D0:((z==1)?D1:D2);
  int wr = w * 32;
  fx4 acc[2][4] = {};
  for (int kt = 0; kt < DIM; kt += 64){
    #pragma unroll
    for (int i = 0; i < 4; i++){
      int p = i*256 + tid;
      int row = p >> 3, cc = p & 7;
      int gc = cc ^ (row & 7);
      GL16(A + (size_t)(m0+row)*DIM + kt + gc*8, As + p*8);
    }
    #pragma unroll
    for (int i = 0; i < 2; i++){
      int p = i*256 + tid;
      int row = p >> 3, cc = p & 7;
      int gc = cc ^ (row & 7);
      GL16(Dw + (size_t)row*DIM + kt + gc*8, Bs + p*8);
    }
    __syncthreads();
    #pragma unroll
    for (int kk = 0; kk < 2; kk++){
      s8v af[2], bfr[4];
      #pragma unroll
      for (int t = 0; t < 2; t++){
        int rowa = wr + t*16 + l15;
        int ca = (kk*4 + l16) ^ (rowa & 7);
        af[t] = *(const s8v*)(As + rowa*64 + ca*8);
      }
      #pragma unroll
      for (int t = 0; t < 4; t++){
        int rowb = t*16 + l15;
        int cb = (kk*4 + l16) ^ (rowb & 7);
        bfr[t] = *(const s8v*)(Bs + rowb*64 + cb*8);
      }
      #pragma unroll
      for (int mt = 0; mt < 2; mt++)
        #pragma unroll
        for (int nt = 0; nt < 4; nt++)
          acc[mt][nt] = MFMA(af[mt], bfr[nt], acc[mt][nt]);
    }
    __syncthreads();
  }
  #pragma unroll
  for (int mt = 0; mt < 2; mt++)
    #pragma unroll
    for (int j = 0; j < 4; j++){
      int row = m0 + wr + mt*16 + l16*4 + j;
      #pragma unroll
      for (int nt = 0; nt < 4; nt++){
        int col = nt*16 + l15;
        outb[((size_t)z*CONDN + row)*64 + col] = f2bf(acc[mt][nt][j]);
      }
    }
}

// ---------------- LoRA up (MFMA): q/k/v rows [2048:3072) += downb @ upW^T ----------------
__global__ __launch_bounds__(256) void lora_up_g(const unsigned short* __restrict__ downb,
                                                 const unsigned short* __restrict__ U0,
                                                 const unsigned short* __restrict__ U1,
                                                 const unsigned short* __restrict__ U2,
                                                 float* __restrict__ q,
                                                 float* __restrict__ k,
                                                 float* __restrict__ v){
  __shared__ unsigned short As[128*64];
  __shared__ unsigned short Bs[128*64];
  int tid = threadIdx.x, lane = tid & 63, w = tid >> 6;
  int l15 = lane & 15, l16 = lane >> 4;
  int z = blockIdx.z;
  int m0 = blockIdx.y * 128, n0 = blockIdx.x * 128;
  const unsigned short* A = downb + (size_t)z*CONDN*64;
  const unsigned short* B = (z==0)?U0:((z==1)?U1:U2);
  float* dst = ((z==0)?q:((z==1)?k:v)) + (size_t)BLK*DIM;
  int wr = (w >> 1) * 64, wc = (w & 1) * 64;
  fx4 acc[4][4] = {};
  #pragma unroll
  for (int i = 0; i < 4; i++){
    int p = i*256 + tid;
    int row = p >> 3, cc = p & 7;
    int gc = cc ^ (row & 7);
    GL16(A + (size_t)(m0+row)*64 + gc*8, As + p*8);
    GL16(B + (size_t)(n0+row)*64 + gc*8, Bs + p*8);
  }
  __syncthreads();
  #pragma unroll
  for (int kk = 0; kk < 2; kk++){
    s8v af[4], bfr[4];
    #pragma unroll
    for (int t = 0; t < 4; t++){
      int rowa = wr + t*16 + l15;
      int ca = (kk*4 + l16) ^ (rowa & 7);
      af[t] = *(const s8v*)(As + rowa*64 + ca*8);
      int rowb = wc + t*16 + l15;
      int cb = (kk*4 + l16) ^ (rowb & 7);
      bfr[t] = *(const s8v*)(Bs + rowb*64 + cb*8);
    }
    #pragma unroll
    for (int mt = 0; mt < 4; mt++)
      #pragma unroll
      for (int nt = 0; nt < 4; nt++)
        acc[mt][nt] = MFMA(af[mt], bfr[nt], acc[mt][nt]);
  }
  #pragma unroll
  for (int mt = 0; mt < 4; mt++)
    #pragma unroll
    for (int j = 0; j < 4; j++){
      int row = m0 + wr + mt*16 + l16*4 + j;
      float* drow = dst + (size_t)row*DIM;
      #pragma unroll
      for (int nt = 0; nt < 4; nt++){
        int col = n0 + wc + nt*16 + l15;
        drow[col] += acc[mt][nt][j];
      }
    }
}

// ---------------- rmsnorm + rope -> bf16 head-major [H][S][HD], output scaled by qscale ----------------
__global__ __launch_bounds__(256) void norm_rope(const float* __restrict__ src,
                                                 unsigned short* __restrict__ dst,
                                                 const float* __restrict__ wt,
                                                 const float* __restrict__ rc,
                                                 const float* __restrict__ rs,
                                                 int S, float qscale){
  int tid = threadIdx.x, lane = tid & 63, w = tid >> 6;
  int r = blockIdx.x*4 + w;
  int pos = r % S, h = r / S;
  const float* x = src + (size_t)pos*DIM + h*HD;
  float2 xv = *(const float2*)(x + 2*lane);
  float ss = xv.x*xv.x + xv.y*xv.y;
  #pragma unroll
  for (int o = 1; o < 64; o <<= 1) ss += __shfl_xor(ss, o);
  float rr = rsqrtf(ss*(1.f/128.f) + 1e-6f);
  float y0 = xv.x*rr*wt[2*lane], y1 = xv.y*rr*wt[2*lane+1];
  float2 cv = *(const float2*)(rc + (size_t)pos*HD + 2*lane);
  float2 sv = *(const float2*)(rs + (size_t)pos*HD + 2*lane);
  float o0 = (y0*cv.x - y1*sv.x)*qscale;
  float o1 = (y1*cv.y + y0*sv.y)*qscale;
  ushort2 ov; ov.x = f2bf(o0); ov.y = f2bf(o1);
  *(ushort2*)(dst + ((size_t)h*S + pos)*HD + 2*lane) = ov;
}

// ---------------- ip_k rmsnorm (eps 1e-5, no weight) -> bf16 [H][64][HD] ----------------
__global__ __launch_bounds__(256) void ipk_norm_bf(const float* __restrict__ src,
                                                   unsigned short* __restrict__ dst){
  int tid = threadIdx.x, lane = tid & 63, w = tid >> 6;
  int r = blockIdx.x*4 + w;         // r < 64*24
  int pos = r / HEADS, h = r % HEADS;
  const float* x = src + (size_t)pos*DIM + h*HD;
  float2 xv = *(const float2*)(x + 2*lane);
  float ss = xv.x*xv.x + xv.y*xv.y;
  #pragma unroll
  for (int o = 1; o < 64; o <<= 1) ss += __shfl_xor(ss, o);
  float rr = rsqrtf(ss*(1.f/128.f) + 1e-5f);
  ushort2 ov; ov.x = f2bf(xv.x*rr); ov.y = f2bf(xv.y*rr);
  *(ushort2*)(dst + ((size_t)h*NIPN + pos)*HD + 2*lane) = ov;
}

// ---------------- ipv -> bf16 [H][HD][64] transpose ----------------
__global__ __launch_bounds__(256) void ipv_transpose(const float* __restrict__ ipv,
                                                     unsigned short* __restrict__ vt){
  int h = blockIdx.x, tid = threadIdx.x;
  #pragma unroll
  for (int i = 0; i < 32; i++){
    int idx = i*256 + tid;       // idx = d*64 + key
    int d = idx >> 6, key = idx & 63;
    vt[((size_t)h*HD + d)*64 + key] = f2bf(ipv[(size_t)key*DIM + h*HD + d]);
  }
}

// ---------------- v -> Vt bf16 [H][HD][SEQ] transpose ----------------
__global__ __launch_bounds__(256) void v_transpose(const float* __restrict__ v,
                                                   unsigned short* __restrict__ Vt){
  __shared__ float t[64][129];
  int h = blockIdx.y, p0 = blockIdx.x*64, tid = threadIdx.x;
  int dcol = tid & 127, prow2 = tid >> 7;
  #pragma unroll
  for (int i = 0; i < 32; i++){
    int pos = i*2 + prow2;
    t[pos][dcol] = v[(size_t)(p0+pos)*DIM + h*HD + dcol];
  }
  __syncthreads();
  int pos = tid & 63, dbase = tid >> 6;
  #pragma unroll
  for (int i = 0; i < 32; i++){
    int d = i*4 + dbase;
    Vt[((size_t)h*HD + d)*SEQN + p0 + pos] = f2bf(t[pos][d]);
  }
}

// ---------------- IP attention (MFMA): 2048 q x 64 keys per head, exact softmax ----------------
__global__ __launch_bounds__(256) void ip_attn_m(const float* __restrict__ qb,
                                                 const unsigned short* __restrict__ ipk_bf,
                                                 const unsigned short* __restrict__ ipv_t,
                                                 float* __restrict__ out){
  __shared__ unsigned short Ks[64*HD];
  __shared__ unsigned short Vs[HD*64];
  __shared__ unsigned short Ps[4][16*64];
  int tid = threadIdx.x, lane = tid & 63, w = tid >> 6;
  int l15 = lane & 15, l16 = lane >> 4;
  int h = blockIdx.y;
  int q0 = blockIdx.x*64 + w*16;
  const unsigned short* Kh = ipk_bf + (size_t)h*NIPN*HD;
  const unsigned short* Vh = ipv_t + (size_t)h*HD*NIPN;

  #pragma unroll
  for (int i = 0; i < 4; i++){
    int p = i*256 + tid;
    int row = p >> 4, cc = p & 15;
    int gc = cc ^ (row & 7);
    GL16(Kh + (size_t)row*HD + gc*8, Ks + p*8);
  }
  #pragma unroll
  for (int i = 0; i < 4; i++){
    int p = i*256 + tid;
    int row = p >> 3, cc = p & 7;
    int gc = cc ^ (row & 7);
    GL16(Vh + (size_t)row*64 + gc*8, Vs + p*8);
  }

  // q fragments from fp32 qb (original_query = pre-norm q, rows < 2048)
  s8v qf[4];
  #pragma unroll
  for (int kf = 0; kf < 4; kf++){
    const float* qp = qb + (size_t)(q0 + l15)*DIM + h*HD + kf*32 + l16*8;
    float4 a = *(const float4*)qp;
    float4 b = *(const float4*)(qp + 4);
    s8v f;
    f[0]=(short)f2bf(a.x); f[1]=(short)f2bf(a.y); f[2]=(short)f2bf(a.z); f[3]=(short)f2bf(a.w);
    f[4]=(short)f2bf(b.x); f[5]=(short)f2bf(b.y); f[6]=(short)f2bf(b.z); f[7]=(short)f2bf(b.w);
    qf[kf] = f;
  }
  __syncthreads();

  fx4 s[4] = {};
  #pragma unroll
  for (int ct = 0; ct < 4; ct++){
    #pragma unroll
    for (int kk = 0; kk < 4; kk++){
      int row = ct*16 + l15;
      int c = (kk*4 + l16) ^ (row & 7);
      s8v b = *(const s8v*)(Ks + row*HD + c*8);
      s[ct] = MFMA(qf[kk], b, s[ct]);
    }
  }
  const float SC = 0.08838834764831845f;
  float lrow[4];
  #pragma unroll
  for (int j = 0; j < 4; j++){
    #pragma unroll
    for (int ct = 0; ct < 4; ct++) s[ct][j] *= SC;
    float v = fmaxf(fmaxf(s[0][j], s[1][j]), fmaxf(s[2][j], s[3][j]));
    #pragma unroll
    for (int o2 = 1; o2 < 16; o2 <<= 1) v = fmaxf(v, __shfl_xor(v, o2));
    float sum = 0.f;
    #pragma unroll
    for (int ct = 0; ct < 4; ct++){
      float p = __expf(s[ct][j] - v);
      s[ct][j] = p;
      sum += p;
    }
    #pragma unroll
    for (int o2 = 1; o2 < 16; o2 <<= 1) sum += __shfl_xor(sum, o2);
    lrow[j] = sum;
  }

  // P -> bf16 via swizzled per-wave LDS
  #pragma unroll
  for (int ct = 0; ct < 4; ct++)
    #pragma unroll
    for (int j = 0; j < 4; j++){
      int row = l16*4 + j;
      int cidx = ct*16 + l15;
      Ps[w][row*64 + (((cidx>>3) ^ (row&7))<<3) + (cidx&7)] = f2bf(s[ct][j]);
    }
  asm volatile("s_waitcnt lgkmcnt(0)" ::: "memory");
  s8v pa[2];
  #pragma unroll
  for (int kk = 0; kk < 2; kk++){
    int c = (kk*4 + l16) ^ (l15 & 7);
    pa[kk] = *(const s8v*)(&Ps[w][l15*64 + c*8]);
  }
  fx4 o[8] = {};
  #pragma unroll
  for (int nt = 0; nt < 8; nt++){
    #pragma unroll
    for (int kk = 0; kk < 2; kk++){
      int row = nt*16 + l15;
      int c = (kk*4 + l16) ^ (row & 7);
      s8v bv = *(const s8v*)(Vs + row*64 + c*8);
      o[nt] = MFMA(pa[kk], bv, o[nt]);
    }
  }
  #pragma unroll
  for (int nt = 0; nt < 8; nt++)
    #pragma unroll
    for (int j = 0; j < 4; j++){
      int row = q0 + l16*4 + j;
      int d = nt*16 + l15;
      out[(size_t)row*DIM + h*HD + d] = o[nt][j] / lrow[j];
    }
}

// ---------------- main flash attention, split-K x2, 8-wave blocks, XCD-chunked ----------------
#define QB 128
#define KVB 64
#define PSTR 72
__global__ __launch_bounds__(512, 4) void flash_attn_split(const unsigned short* __restrict__ Qn,
                                                           const unsigned short* __restrict__ Kn,
                                                           const unsigned short* __restrict__ Vt,
                                                           float* __restrict__ po0,
                                                           float* __restrict__ po1,
                                                           float* __restrict__ pm,
                                                           float* __restrict__ pl){
  __shared__ unsigned short Ks[KVB*HD];     // 16 KB
  __shared__ unsigned short Vs[HD*KVB];     // 16 KB
  __shared__ unsigned short Ps[8][16*PSTR]; // 18 KB
  int tid = threadIdx.x, lane = tid & 63, w = tid >> 6;
  int l15 = lane & 15, l16 = lane >> 4;
  // XCD-chunked bijective swizzle: 768 blocks, 8 XCDs, 96 logical/XCD.
  int b = blockIdx.x;
  int swz = (b & 7) * 96 + (b >> 3);
  int sp = swz / 384;
  int rem = swz - sp*384;
  int h = rem >> 4;
  int qt = rem & 15;
  int q0 = qt*QB + w*16;
  const unsigned short* Qh = Qn + (size_t)h*BLK*HD;
  const unsigned short* Kh = Kn + (size_t)h*SEQN*HD;
  const unsigned short* Vh = Vt + (size_t)h*HD*SEQN;
  const int kvbase = sp * (SEQN/2);
  const int NT = (SEQN/2) / KVB;   // 24 tiles

  s8v qf[4];
  #pragma unroll
  for (int kf = 0; kf < 4; kf++)
    qf[kf] = *(const s8v*)(Qh + (size_t)(q0 + l15)*HD + kf*32 + l16*8);

  fx4 o[8] = {};
  float mrow[4], lrow[4];
  #pragma unroll
  for (int j = 0; j < 4; j++){ mrow[j] = -1e30f; lrow[j] = 0.f; }

  for (int t = 0; t < NT; t++){
    int kv0 = kvbase + t*KVB;
    // stage K (1024 x 16B) + V (1024 x 16B) across 512 threads
    #pragma unroll
    for (int i = 0; i < 2; i++){
      int p = i*512 + tid;
      int row = p >> 4, cc = p & 15;
      int gc = cc ^ (row & 7);
      GL16(Kh + (size_t)(kv0+row)*HD + gc*8, Ks + p*8);
    }
    #pragma unroll
    for (int i = 0; i < 2; i++){
      int p = i*512 + tid;
      int row = p >> 3, cc = p & 7;
      int gc = cc ^ (row & 7);
      GL16(Vh + (size_t)row*SEQN + kv0 + gc*8, Vs + p*8);
    }
    __syncthreads();   // drains vmcnt: K/V ready

    fx4 s[4] = {};
    #pragma unroll
    for (int ct = 0; ct < 4; ct++){
      #pragma unroll
      for (int kk = 0; kk < 4; kk++){
        int row = ct*16 + l15;
        int c = (kk*4 + l16) ^ (row & 7);
        s8v bb = *(const s8v*)(Ks + row*HD + c*8);
        s[ct] = MFMA(qf[kk], bb, s[ct]);
      }
    }
    float pmax[4], rssum[4];
    #pragma unroll
    for (int j = 0; j < 4; j++){
      float v = fmaxf(fmaxf(s[0][j], s[1][j]), fmaxf(s[2][j], s[3][j]));
      #pragma unroll
      for (int o2 = 1; o2 < 16; o2 <<= 1) v = fmaxf(v, __shfl_xor(v, o2));
      pmax[j] = v;
      rssum[j] = 0.f;
    }
    float need = 0.f;
    #pragma unroll
    for (int j = 0; j < 4; j++) need = fmaxf(need, pmax[j] - mrow[j]);
    if (__any(need > 8.f)){
      float alpha[4];
      #pragma unroll
      for (int j = 0; j < 4; j++){
        float mnew = fmaxf(mrow[j], pmax[j]);
        alpha[j] = __expf(mrow[j] - mnew);
        mrow[j] = mnew;
      }
      #pragma unroll
      for (int nt = 0; nt < 8; nt++)
        #pragma unroll
        for (int j = 0; j < 4; j++) o[nt][j] *= alpha[j];
      #pragma unroll
      for (int j = 0; j < 4; j++) lrow[j] *= alpha[j];
    }
    #pragma unroll
    for (int ct = 0; ct < 4; ct++)
      #pragma unroll
      for (int j = 0; j < 4; j++){
        float p = __expf(s[ct][j] - mrow[j]);
        s[ct][j] = p;
        rssum[j] += p;
      }
    #pragma unroll
    for (int j = 0; j < 4; j++){
      #pragma unroll
      for (int o2 = 1; o2 < 16; o2 <<= 1) rssum[j] += __shfl_xor(rssum[j], o2);
      lrow[j] += rssum[j];
    }

    // P -> bf16 per-wave LDS, stride 72
    #pragma unroll
    for (int ct = 0; ct < 4; ct++)
      #pragma unroll
      for (int j = 0; j < 4; j++){
        int row = l16*4 + j;
        int cidx = ct*16 + l15;
        Ps[w][row*PSTR + cidx] = f2bf(s[ct][j]);
      }
    asm volatile("s_waitcnt lgkmcnt(0)" ::: "memory");
    s8v pa[2];
    #pragma unroll
    for (int kk = 0; kk < 2; kk++)
      pa[kk] = *(const s8v*)(&Ps[w][l15*PSTR + (kk*4 + l16)*8]);
    #pragma unroll
    for (int nt = 0; nt < 8; nt++){
      #pragma unroll
      for (int kk = 0; kk < 2; kk++){
        int row = nt*16 + l15;
        int c = (kk*4 + l16) ^ (row & 7);
        s8v bvv = *(const s8v*)(Vs + row*KVB + c*8);
        o[nt] = MFMA(pa[kk], bvv, o[nt]);
      }
    }
    __syncthreads();   // all waves done reading before next stage overwrites
  }

  float* pop = sp ? po1 : po0;
  #pragma unroll
  for (int nt = 0; nt < 8; nt++)
    #pragma unroll
    for (int j = 0; j < 4; j++){
      int row = q0 + l16*4 + j;
      int d = nt*16 + l15;
      pop[((size_t)h*BLK + row)*HD + d] = o[nt][j];
    }
  if (l15 == 0){
    #pragma unroll
    for (int j = 0; j < 4; j++){
      int row = q0 + l16*4 + j;
      pm[(size_t)sp*HEADS*BLK + h*BLK + row] = mrow[j];
      pl[(size_t)sp*HEADS*BLK + h*BLK + row] = lrow[j];
    }
  }
}

// ---------------- merge the two split-K halves into out (+=) ----------------
__global__ __launch_bounds__(256) void flash_merge(const float* __restrict__ po0,
                                                   const float* __restrict__ po1,
                                                   const float* __restrict__ pm,
                                                   const float* __restrict__ pl,
                                                   float* __restrict__ out){
  int tid = threadIdx.x, lane = tid & 63, w = tid >> 6;
  int r = blockIdx.x*4 + w;        // r < HEADS*BLK
  int h = r >> 11, pos = r & 2047;
  float m0 = pm[r], m1 = pm[HEADS*BLK + r];
  float l0 = pl[r], l1 = pl[HEADS*BLK + r];
  float mx = fmaxf(m0, m1);
  float a0 = __expf(m0 - mx), a1 = __expf(m1 - mx);
  float li = 1.f / (l0*a0 + l1*a1);
  float s0 = a0*li, s1 = a1*li;
  size_t base = ((size_t)h*BLK + pos)*HD + 2*lane;
  float2 x0 = *(const float2*)(po0 + base);
  float2 x1 = *(const float2*)(po1 + base);
  float* op = out + (size_t)pos*DIM + h*HD + 2*lane;
  float2 cv = *(const float2*)op;
  cv.x += x0.x*s0 + x1.x*s1;
  cv.y += x0.y*s0 + x1.y*s1;
  *(float2*)op = cv;
}

extern "C" void kernel_launch(void* const* d_in, const int* in_sizes, int n_in,
                              void* d_out, int out_size, void* d_ws, size_t ws_size,
                              hipStream_t stream){
  (void)in_sizes; (void)n_in; (void)out_size;
  const float* hs       = (const float*)d_in[0];
  const float* image_emb= (const float*)d_in[1];
  const float* rope_cos = (const float*)d_in[2];
  const float* rope_sin = (const float*)d_in[3];
  const float* wq = (const float*)d_in[4];
  const float* bq = (const float*)d_in[5];
  const float* wk = (const float*)d_in[6];
  const float* bk = (const float*)d_in[7];
  const float* wv = (const float*)d_in[8];
  const float* bv = (const float*)d_in[9];
  const float* norm_q_w = (const float*)d_in[10];
  const float* norm_k_w = (const float*)d_in[11];
  const float* q_down = (const float*)d_in[12];
  const float* q_up   = (const float*)d_in[13];
  const float* k_down = (const float*)d_in[14];
  const float* k_up   = (const float*)d_in[15];
  const float* v_down = (const float*)d_in[16];
  const float* v_up   = (const float*)d_in[17];
  const float* wk_ip  = (const float*)d_in[18];
  const float* wv_ip  = (const float*)d_in[19];
  float* out = (float*)d_out;

  char* ws = (char*)d_ws;
  size_t off = 0;
  auto alloc = [&](size_t bytes){ void* p = ws + off; off += (bytes + 255) & ~(size_t)255; return p; };
  unsigned short* hs_bf = (unsigned short*)alloc((size_t)SEQN*DIM*2);
  unsigned short* w_bf  = (unsigned short*)alloc((size_t)DIM*DIM*2);
  unsigned short* wk_bf = (unsigned short*)alloc((size_t)DIM*DIM*2);
  unsigned short* wv_bf = (unsigned short*)alloc((size_t)DIM*DIM*2);
  unsigned short* ie_bf = (unsigned short*)alloc((size_t)NIPN*DIM*2);
  float* qb = (float*)alloc((size_t)SEQN*DIM*4);
  float* kb = (float*)alloc((size_t)SEQN*DIM*4);
  float* vb = (float*)alloc((size_t)SEQN*DIM*4);
  float* ipk_pre = (float*)alloc((size_t)NIPN*DIM*4);
  float* ipv_pre = (float*)alloc((size_t)NIPN*DIM*4);
  unsigned short* ipk_bf = (unsigned short*)alloc((size_t)HEADS*NIPN*HD*2);
  unsigned short* ipv_t  = (unsigned short*)alloc((size_t)HEADS*HD*NIPN*2);
  unsigned short* dwn_bf[3];
  unsigned short* upw_bf[3];
  for (int i = 0; i < 3; i++) dwn_bf[i] = (unsigned short*)alloc((size_t)RANKN*DIM*2);
  for (int i = 0; i < 3; i++) upw_bf[i] = (unsigned short*)alloc((size_t)DIM*RANKN*2);
  unsigned short* downb_bf = (unsigned short*)alloc((size_t)3*CONDN*RANKN*2);
  unsigned short* Qn = (unsigned short*)alloc((size_t)HEADS*BLK*HD*2);
  unsigned short* Kn = (unsigned short*)alloc((size_t)HEADS*SEQN*HD*2);
  unsigned short* Vt = (unsigned short*)alloc((size_t)HEADS*HD*SEQN*2);
  if (off > ws_size) return;  // workspace too small -> leave output poisoned (visible failure)

  // split-K partials alias dead buffers (qb/kb/vb fully consumed before flash_attn_split)
  float* po0 = qb;
  float* po1 = kb;
  float* pm  = vb;
  float* pl  = vb + (size_t)2*HEADS*BLK;

  int n4;
  n4 = SEQN*DIM/4;
  cvt_f32_bf16<<<(n4+255)/256, 256, 0, stream>>>(hs, hs_bf, n4);
  n4 = NIPN*DIM/4;
  cvt_f32_bf16<<<(n4+255)/256, 256, 0, stream>>>(image_emb, ie_bf, n4);

  n4 = DIM*DIM/4;
  cvt_f32_bf16<<<(n4+255)/256, 256, 0, stream>>>(wq, w_bf, n4);
  cvt_f32_bf16<<<(n4+255)/256, 256, 0, stream>>>(wk, wk_bf, n4);
  cvt_f32_bf16<<<(n4+255)/256, 256, 0, stream>>>(wv, wv_bf, n4);
  gemm_qkv<<<dim3(72, SEQN/BM), 256, 0, stream>>>(hs_bf, w_bf, wk_bf, wv_bf,
      qb, kb, vb, bq, bk, bv);

  dim3 gip(DIM/BN, 1);
  cvt_f32_bf16<<<(n4+255)/256, 256, 0, stream>>>(wk_ip, w_bf, n4);
  gemm_bf16<<<gip, 256, 0, stream>>>(ie_bf, w_bf, ipk_pre, nullptr, NIPN);
  cvt_f32_bf16<<<(n4+255)/256, 256, 0, stream>>>(wv_ip, w_bf, n4);
  gemm_bf16<<<gip, 256, 0, stream>>>(ie_bf, w_bf, ipv_pre, nullptr, NIPN);

  // LoRA path (MFMA)
  n4 = RANKN*DIM/4;
  cvt_f32_bf16<<<(n4+255)/256, 256, 0, stream>>>(q_down, dwn_bf[0], n4);
  cvt_f32_bf16<<<(n4+255)/256, 256, 0, stream>>>(k_down, dwn_bf[1], n4);
  cvt_f32_bf16<<<(n4+255)/256, 256, 0, stream>>>(v_down, dwn_bf[2], n4);
  cvt_f32_bf16<<<(n4+255)/256, 256, 0, stream>>>(q_up, upw_bf[0], n4);
  cvt_f32_bf16<<<(n4+255)/256, 256, 0, stream>>>(k_up, upw_bf[1], n4);
  cvt_f32_bf16<<<(n4+255)/256, 256, 0, stream>>>(v_up, upw_bf[2], n4);
  lora_down_g<<<dim3(1, CONDN/128, 3), 256, 0, stream>>>(hs_bf + (size_t)BLK*DIM,
      dwn_bf[0], dwn_bf[1], dwn_bf[2], downb_bf);
  lora_up_g<<<dim3(DIM/128, CONDN/128, 3), 256, 0, stream>>>(downb_bf,
      upw_bf[0], upw_bf[1], upw_bf[2], qb, kb, vb);

  ipk_norm_bf<<<(NIPN*HEADS)/4, 256, 0, stream>>>(ipk_pre, ipk_bf);
  ipv_transpose<<<HEADS, 256, 0, stream>>>(ipv_pre, ipv_t);
  const float SC = 0.08838834764831845f;
  norm_rope<<<(BLK*HEADS)/4, 256, 0, stream>>>(qb, Qn, norm_q_w, rope_cos, rope_sin, BLK, SC);
  norm_rope<<<(SEQN*HEADS)/4, 256, 0, stream>>>(kb, Kn, norm_k_w, rope_cos, rope_sin, SEQN, 1.0f);
  v_transpose<<<dim3(SEQN/64, HEADS), 256, 0, stream>>>(vb, Vt);

  ip_attn_m<<<dim3(BLK/64, HEADS), 256, 0, stream>>>(qb, ipk_bf, ipv_t, out);
  // qb/kb/vb dead from here: reused as split-K partial buffers
  flash_attn_split<<<768, 512, 0, stream>>>(Qn, Kn, Vt, po0, po1, pm, pl);
  flash_merge<<<(HEADS*BLK)/4, 256, 0, stream>>>(po0, po1, pm, pl, out);
}